// Round 12
// baseline (210.602 us; speedup 1.0000x reference)
//
#include <hip/hip_runtime.h>

typedef __attribute__((ext_vector_type(8))) short short8;
typedef __attribute__((ext_vector_type(8))) _Float16 half8;
typedef __attribute__((ext_vector_type(2))) float f32x2;
typedef __attribute__((ext_vector_type(4))) float f32x4;
typedef __attribute__((ext_vector_type(16))) float f32x16;

__device__ __forceinline__ unsigned short f2bf(float f) {
  unsigned int u = __float_as_uint(f);
  u += 0x7fffu + ((u >> 16) & 1u);   // round-to-nearest-even
  return (unsigned short)(u >> 16);
}
__device__ __forceinline__ float bf2f(unsigned short h) {
  return __uint_as_float(((unsigned int)h) << 16);
}
// HW packed f32->bf16 (RNE): 1 instr (low=a, high=b)
__device__ __forceinline__ unsigned int cvtpk(float a, float b) {
  unsigned int r;
  asm("v_cvt_pk_bf16_f32 %0, %1, %2" : "=v"(r) : "v"(a), "v"(b));
  return r;
}
// f32 -> fp16 bits (RNE)
__device__ __forceinline__ unsigned short f2h(float f) {
  unsigned int r;
  asm("v_cvt_f16_f32 %0, %1" : "=v"(r) : "v"(f));
  return (unsigned short)r;
}
__device__ __forceinline__ float lo16f(unsigned int u) { return __uint_as_float(u << 16); }
__device__ __forceinline__ float hi16f(unsigned int u) { return __uint_as_float(u & 0xffff0000u); }
__device__ __forceinline__ short8 ld8(const unsigned short* p) {
  return *(const short8*)p;
}
__device__ __forceinline__ half8 ld8h(const unsigned short* p) {
  return *(const half8*)p;
}
__device__ __forceinline__ int swap23(int x) {  // swap bits 2<->3
  return (x & 0x13) | ((x & 4) << 1) | ((x & 8) >> 1);
}
// R15: VALU-only exp2. R14's occupancy-doubling null + per-pipe accounting
// fingered the per-CU transcendental unit as the invariant 131k-cyc wall
// (8192 wave-exp2/CU x ~16cyc). Poly: z = n+f, 2^f deg-3 minimax on [0,1)
// (rel err ~1.5e-4 << bf16 0.4% rounding), ldexp via exponent add — safe
// because |z| <~ 50 (same bound behind the fixed-max softmax). ~8 VALU ops
// replace 1 trans op; runs on the 4-SIMD-wide VALU instead of the shared
// trans unit.
__device__ __forceinline__ float exp2p(float z) {
  float nf = floorf(z);
  float f = z - nf;
  float p = fmaf(0.079204430f, f, 0.224338339f);
  p = fmaf(p, f, 0.696457318f);
  p = fmaf(p, f, 0.999892986f);
  int sc = ((int)nf + 127) << 23;
  return p * __int_as_float(sc);
}
#define MFMA(a, b, c) __builtin_amdgcn_mfma_f32_16x16x32_bf16((a), (b), (c), 0, 0, 0)
#define MFMA32(a, b, c) __builtin_amdgcn_mfma_f32_32x32x16_bf16((a), (b), (c), 0, 0, 0)
#define MFMA32H(a, b, c) __builtin_amdgcn_mfma_f32_32x32x16_f16((a), (b), (c), 0, 0, 0)
#define LOG2E 1.4426950408889634f

typedef const __attribute__((address_space(1))) unsigned int* gas_u32p;
typedef __attribute__((address_space(3))) unsigned int* las_u32p;

// ---------------------------------------------------------------------------
// Kernel 1: weight prep. Wcat^T hi/lo bf16 [192][256] (rows 0-31 Wq^T, 32-63
// Wk^T, 64-191 Wv^T), WoT bf16 [256][128].
// ---------------------------------------------------------------------------
__global__ void prep_weights(const float* __restrict__ Wq, const float* __restrict__ Wk,
                             const float* __restrict__ Wv, const float* __restrict__ Wo,
                             unsigned short* __restrict__ Wth, unsigned short* __restrict__ Wtl,
                             unsigned short* __restrict__ WoT) {
  int idx = blockIdx.x * 256 + threadIdx.x;
  if (idx < 192 * 256) {
    int o = idx >> 8, c = idx & 255;
    float w = (o < 32) ? Wq[c * 32 + o] : (o < 64) ? Wk[c * 32 + (o - 32)] : Wv[c * 128 + (o - 64)];
    unsigned short h = f2bf(w);
    Wth[idx] = h;
    Wtl[idx] = f2bf(w - bf2f(h));
  } else if (idx < 192 * 256 + 256 * 128) {
    int j = idx - 192 * 256;
    int c = j >> 7, d = j & 127;
    WoT[j] = f2bf(Wo[d * 256 + c]);
  }
}

// ---------------------------------------------------------------------------
// Kernel 2: QKV projection (R12 layout, measured good). 32 pixels/block.
// Vectorized 8B stores via per-branch MFMA operand order:
//   q/k: D[outc][pixel]; V: D[pixel][dv].
// KVF fused fragment-major buffer, 20KB per nt-tile:
//   KVF[b*64+nt] : [0,2048)    kh fp16 frags [kt(2)][step(2)][lane(64)][e(8)]
//                  [2048,10240) V bf16 frags [dt(4)][ks(4)][lane(64)][e(8)]
// ---------------------------------------------------------------------------
__global__ __launch_bounds__(256) void proj_qkv(
    const float* __restrict__ x,
    const unsigned short* __restrict__ Wth, const unsigned short* __restrict__ Wtl,
    const float* __restrict__ bq, const float* __restrict__ bk, const float* __restrict__ bv,
    unsigned short* __restrict__ qh, unsigned short* __restrict__ KVF) {
  __shared__ unsigned short xsh[32][264];
  __shared__ unsigned short xsl[32][264];
  const int pix0 = blockIdx.x * 32;
  const int b = pix0 >> 12;
  const int nloc0 = pix0 & 4095;
  const int tid = threadIdx.x;

#pragma unroll
  for (int i = 0; i < 8; ++i) {
    int chunk = i * 256 + tid;
    int row = chunk >> 6;
    int c4 = (chunk & 63) * 4;
    float4 v = *(const float4*)(x + (size_t)(pix0 + row) * 256 + c4);
    unsigned int h01 = cvtpk(v.x, v.y), h23 = cvtpk(v.z, v.w);
    unsigned int l01 = cvtpk(v.x - lo16f(h01), v.y - hi16f(h01));
    unsigned int l23 = cvtpk(v.z - lo16f(h23), v.w - hi16f(h23));
    uint2 hp, lp;
    hp.x = h01; hp.y = h23;
    lp.x = l01; lp.y = l23;
    *(uint2*)&xsh[row][c4] = hp;
    *(uint2*)&xsl[row][c4] = lp;
  }
  __syncthreads();

  const int wave = tid >> 6, lane = tid & 63, l = lane & 15, qd = lane >> 4;
  // Block-constant fragment geometry (nloc0 is a multiple of 32):
  const int nt = nloc0 >> 6;
  const int ktc = (nloc0 >> 5) & 1;       // k-frag kt
  const int ksbase = (nloc0 >> 4) & 2;    // v-frag ks base
  const int hh = qd >> 1;
  const int eb = 4 * (qd & 1);

#pragma unroll
  for (int si = 0; si < 3; ++si) {
    const int sub = wave + si * 4;
    const int outc0 = sub * 16;
    if (si == 0) {  // q/k: D[outc][pixel], split-x precision, fp16 output
      const float* bp = (outc0 < 32) ? (bq + outc0) : (bk + outc0 - 32);
      const float4 bb = *(const float4*)(bp + 4 * qd);
      f32x4 acc[2];
      acc[0] = (f32x4){bb.x, bb.y, bb.z, bb.w};
      acc[1] = (f32x4){bb.x, bb.y, bb.z, bb.w};
#pragma unroll
      for (int kc = 0; kc < 8; ++kc) {
        short8 whf = ld8(Wth + (size_t)(outc0 + l) * 256 + kc * 32 + qd * 8);
        short8 wlf = ld8(Wtl + (size_t)(outc0 + l) * 256 + kc * 32 + qd * 8);
#pragma unroll
        for (int m = 0; m < 2; ++m) {
          short8 xhf = ld8(&xsh[m * 16 + l][kc * 32 + qd * 8]);
          short8 xlf = ld8(&xsl[m * 16 + l][kc * 32 + qd * 8]);
          acc[m] = MFMA(wlf, xhf, acc[m]);   // w_lo * x_hi
          acc[m] = MFMA(whf, xlf, acc[m]);   // w_hi * x_lo
          acc[m] = MFMA(whf, xhf, acc[m]);   // w_hi * x_hi
        }
      }
      if (outc0 < 32) {  // q: lane holds outc0+4qd+r for pixel pix0+m*16+l
#pragma unroll
        for (int m = 0; m < 2; ++m) {
          const size_t pixel = (size_t)pix0 + m * 16 + l;
          uint2 st;
          st.x = (unsigned int)f2h(acc[m][0] * LOG2E) |
                 ((unsigned int)f2h(acc[m][1] * LOG2E) << 16);
          st.y = (unsigned int)f2h(acc[m][2] * LOG2E) |
                 ((unsigned int)f2h(acc[m][3] * LOG2E) << 16);
          *(uint2*)(qh + pixel * 32 + outc0 + 4 * qd) = st;
        }
      } else {  // k: kd = (outc0-32)+4qd+r -> step fixed, e run of 4
        const int step = (outc0 - 32) >> 4;
#pragma unroll
        for (int m = 0; m < 2; ++m) {
          const int lpos = swap23(m * 16 + l);
          const size_t koff = (size_t)(b * 64 + nt) * 10240 +
                              (ktc * 2 + step) * 512 + (hh * 32 + lpos) * 8 + eb;
          uint2 st;
          st.x = (unsigned int)f2h(acc[m][0]) | ((unsigned int)f2h(acc[m][1]) << 16);
          st.y = (unsigned int)f2h(acc[m][2]) | ((unsigned int)f2h(acc[m][3]) << 16);
          *(uint2*)(KVF + koff) = st;
        }
      }
    } else {  // v: D[pixel][dv] -> lane holds 4 consecutive pixels for dv=dv0+l
      const int dv = (outc0 - 64) + l;
      const float bias = bv[dv];
      f32x4 acc[2];
      acc[0] = (f32x4){bias, bias, bias, bias};
      acc[1] = (f32x4){bias, bias, bias, bias};
#pragma unroll
      for (int kc = 0; kc < 8; ++kc) {
        short8 whf = ld8(Wth + (size_t)(outc0 + l) * 256 + kc * 32 + qd * 8);
#pragma unroll
        for (int m = 0; m < 2; ++m) {
          short8 xhf = ld8(&xsh[m * 16 + l][kc * 32 + qd * 8]);
          acc[m] = MFMA(xhf, whf, acc[m]);  // D = x * Wv
        }
      }
      const int dt = dv >> 5, lam = dv & 31;
#pragma unroll
      for (int m = 0; m < 2; ++m) {
        const int ks = ksbase + m;
        const size_t voff = (size_t)(b * 64 + nt) * 10240 + 2048 +
                            (dt * 4 + ks) * 512 + (hh * 32 + lam) * 8 + eb;
        uint2 st;
        st.x = cvtpk(acc[m][0], acc[m][1]);
        st.y = cvtpk(acc[m][2], acc[m][3]);
        *(uint2*)(KVF + voff) = st;
      }
    }
  }
}

// ---------------------------------------------------------------------------
// Kernel 3: flash attention. R15 = R14 structure (1 q-tile/wave, 4 waves/SIMD,
// 1024 blocks = 4 blocks/CU, LDS 4x40KB = 160KB) with the poly exp2 (exp2p)
// replacing v_exp_f32. R14's null at doubled occupancy proved a throughput
// wall invariant across all configs; the only invariant count matching the
// measured 131k cyc/CU is exp2 on a per-CU shared trans unit (8192 x ~16cyc).
// exp2p moves that work to the 4-SIMD VALU (~33k cyc/CU added, wall removed).
// ---------------------------------------------------------------------------
__device__ __forceinline__ void stage_kv(const unsigned short* __restrict__ src,
                                         unsigned short* dst, int wave, int lane) {
#pragma unroll
  for (int i = 0; i < 5; ++i) {
    const int c = wave * 5 + i;  // 20 x 1KB chunks, linear copy
    __builtin_amdgcn_global_load_lds(
        (gas_u32p)(const void*)(src + c * 512 + lane * 8),
        (las_u32p)(void*)(dst + c * 512), 16, 0, 0);
  }
}

__global__ __launch_bounds__(256, 4) void flash_attn(
    const unsigned short* __restrict__ qh,
    const unsigned short* __restrict__ KVF, unsigned short* __restrict__ opart,
    float* __restrict__ lstat) {
  __shared__ unsigned short kv[2][10240];   // 2 x 20KB double buffer
  const int b = blockIdx.x & 7;
  const int r7 = blockIdx.x >> 3;      // 0..127
  const int tile = r7 & 31;            // 0..31 (128-query tiles)
  const int split = r7 >> 5;           // 0..3
  const int wave = threadIdx.x >> 6;
  const int lane = threadIdx.x & 63;
  const int lam = lane & 31;           // query index within 32-tile
  const int h = lane >> 5;             // half-wave
  const int m0 = tile * 128 + wave * 32;
  const int nt0 = split * 16;

  const unsigned short* qh_b = qh + (size_t)b * 4096 * 32;
  const unsigned short* kv_b = KVF + (size_t)b * 64 * 10240;

  // Q B-frags (persistent, fp16): B[k=dim 16*step+8h+j][n=query lam]
  half8 qf[2];
#pragma unroll
  for (int step = 0; step < 2; ++step)
    qf[step] = ld8h(qh_b + (size_t)(m0 + lam) * 32 + step * 16 + h * 8);

  f32x16 acc[4];
#pragma unroll
  for (int dt = 0; dt < 4; ++dt)
#pragma unroll
    for (int e = 0; e < 16; ++e) acc[dt][e] = 0.f;
  f32x2 lr = (f32x2){0.f, 0.f};

  stage_kv(kv_b + (size_t)nt0 * 10240, &kv[0][0], wave, lane);
  __syncthreads();

  int cur = 0;
#pragma unroll 1
  for (int it = 0; it < 16; ++it) {
    if (it < 15)   // prefetch next tile into the other buffer
      stage_kv(kv_b + (size_t)(nt0 + it + 1) * 10240, &kv[cur ^ 1][0], wave, lane);

    const unsigned short* cb = &kv[cur][0];

    // ===== kt = 0: QK =====
    half8 k0a = ld8h(cb + 0 * 512 + lane * 8);
    half8 k0b = ld8h(cb + 1 * 512 + lane * 8);
    f32x16 z;
#pragma unroll
    for (int e = 0; e < 16; ++e) z[e] = 0.f;
    __builtin_amdgcn_s_setprio(1);
    z = MFMA32H(k0a, qf[0], z);
    z = MFMA32H(k0b, qf[1], z);
    __builtin_amdgcn_s_setprio(0);
    // poly exp2 + pack (kt=0)
    unsigned int ppA[8];
#pragma unroll
    for (int g = 0; g < 8; ++g) {
      float a0 = exp2p(z[2 * g]);
      float a1 = exp2p(z[2 * g + 1]);
      lr += (f32x2){a0, a1};
      ppA[g] = cvtpk(a0, a1);
    }

    // ===== kt = 1 QK + PV(kt=0) in one MFMA burst =====
    half8 k1a = ld8h(cb + 2 * 512 + lane * 8);
    half8 k1b = ld8h(cb + 3 * 512 + lane * 8);
    f32x16 w;
#pragma unroll
    for (int e = 0; e < 16; ++e) w[e] = 0.f;
    __builtin_amdgcn_s_setprio(1);
    w = MFMA32H(k1a, qf[0], w);
    w = MFMA32H(k1b, qf[1], w);
#pragma unroll
    for (int kss = 0; kss < 2; ++kss) {   // ks = 0,1
      union { unsigned int u[4]; short8 v; } pf;
#pragma unroll
      for (int j = 0; j < 4; ++j) pf.u[j] = ppA[4 * kss + j];
#pragma unroll
      for (int dt = 0; dt < 4; ++dt) {
        short8 vfrag = *(const short8*)(cb + 2048 + (dt * 4 + kss) * 512 + lane * 8);
        acc[dt] = MFMA32(vfrag, pf.v, acc[dt]);
      }
    }
    __builtin_amdgcn_s_setprio(0);
    // poly exp2 + pack (kt=1)
    unsigned int ppB[8];
#pragma unroll
    for (int g = 0; g < 8; ++g) {
      float a0 = exp2p(w[2 * g]);
      float a1 = exp2p(w[2 * g + 1]);
      lr += (f32x2){a0, a1};
      ppB[g] = cvtpk(a0, a1);
    }
    // ===== PV(kt=1) =====
    __builtin_amdgcn_s_setprio(1);
#pragma unroll
    for (int kss = 0; kss < 2; ++kss) {   // ks = 2,3
      union { unsigned int u[4]; short8 v; } pf;
#pragma unroll
      for (int j = 0; j < 4; ++j) pf.u[j] = ppB[4 * kss + j];
#pragma unroll
      for (int dt = 0; dt < 4; ++dt) {
        short8 vfrag = *(const short8*)(cb + 2048 + (dt * 4 + 2 + kss) * 512 + lane * 8);
        acc[dt] = MFMA32(vfrag, pf.v, acc[dt]);
      }
    }
    __builtin_amdgcn_s_setprio(0);

    __syncthreads();   // next-buffer staging landed; all waves done with cur
    cur ^= 1;
  }

  // Epilogue: combine l across half-waves, store unnormalized partials.
  const float lrun = lr.x + lr.y;
  const float ltot = lrun + __shfl_xor(lrun, 32);
  const int grow = b * 4096 + m0 + lam;
  if (h == 0) lstat[split * 32768 + grow] = ltot;
  const size_t obase = ((size_t)split * 32768 + grow) * 128;
#pragma unroll
  for (int dt = 0; dt < 4; ++dt)
#pragma unroll
    for (int g = 0; g < 8; ++g) {
      int r = 2 * g;
      int dv = dt * 32 + (r & 3) + 8 * (r >> 2) + 4 * h;
      *(unsigned int*)(opart + obase + dv) = cvtpk(acc[dt][r], acc[dt][r + 1]);
    }
}

// ---------------------------------------------------------------------------
// Kernel 3b (fallback path): combine split-K partials -> ao (bf16).
// ---------------------------------------------------------------------------
__global__ __launch_bounds__(256) void combine_splits(
    const unsigned short* __restrict__ opart, const float* __restrict__ lstat,
    unsigned short* __restrict__ ao) {
  const int tid = threadIdx.x;
  const int row = blockIdx.x * 16 + (tid >> 4);
  const int col = (tid & 15) * 8;
  float den = lstat[row] + lstat[32768 + row] + lstat[65536 + row] + lstat[98304 + row];
  float inv = 1.f / den;
  float o[8] = {0.f, 0.f, 0.f, 0.f, 0.f, 0.f, 0.f, 0.f};
#pragma unroll
  for (int s = 0; s < 4; ++s) {
    uint4 v = *(const uint4*)(opart + ((size_t)s * 32768 + row) * 128 + col);
    unsigned int uu[4] = {v.x, v.y, v.z, v.w};
#pragma unroll
    for (int j = 0; j < 4; ++j) {
      o[2 * j]     += bf2f((unsigned short)(uu[j] & 0xffff));
      o[2 * j + 1] += bf2f((unsigned short)(uu[j] >> 16));
    }
  }
  uint4 outv;
  outv.x = cvtpk(o[0] * inv, o[1] * inv);
  outv.y = cvtpk(o[2] * inv, o[3] * inv);
  outv.z = cvtpk(o[4] * inv, o[5] * inv);
  outv.w = cvtpk(o[6] * inv, o[7] * inv);
  *(uint4*)(ao + (size_t)row * 128 + col) = outv;
}

// ---------------------------------------------------------------------------
// Kernel 4 (fallback path): output projection + bias + residual.
// ---------------------------------------------------------------------------
__global__ __launch_bounds__(256) void out_proj(
    const unsigned short* __restrict__ ao, const unsigned short* __restrict__ WoT,
    const float* __restrict__ bo, const float* __restrict__ x, float* __restrict__ out) {
  const int pix0 = blockIdx.x * 64;
  const int wave = threadIdx.x >> 6, lane = threadIdx.x & 63, l = lane & 15, qd = lane >> 4;
  const int base = pix0 + wave * 16;
  short8 af[4];
#pragma unroll
  for (int kc = 0; kc < 4; ++kc)
    af[kc] = ld8(ao + (size_t)(base + l) * 128 + kc * 32 + qd * 8);
#pragma unroll
  for (int sub = 0; sub < 16; ++sub) {
    const int c0 = sub * 16 + 4 * qd;
    float4 bb = *(const float4*)(bo + c0);
    f32x4 acc = (f32x4){bb.x, bb.y, bb.z, bb.w};
#pragma unroll
    for (int kc = 0; kc < 4; ++kc) {
      short8 wf = ld8(WoT + (size_t)(sub * 16 + l) * 128 + kc * 32 + qd * 8);
      acc = MFMA(wf, af[kc], acc);   // D[c][pixel]
    }
    float4 xv = *(const float4*)(x + (size_t)(base + l) * 256 + c0);
    float4 res;
    res.x = acc[0] + xv.x;
    res.y = acc[1] + xv.y;
    res.z = acc[2] + xv.z;
    res.w = acc[3] + xv.w;
    *(float4*)(out + (size_t)(base + l) * 256 + c0) = res;
  }
}

// ---------------------------------------------------------------------------
// Kernel 4f (fused path): combine + output projection in ONE kernel.
// opart lives in WORKSPACE (no aliasing with the d_out output write).
// ---------------------------------------------------------------------------
__global__ __launch_bounds__(256) void combine_out(
    const unsigned short* __restrict__ opart, const float* __restrict__ lstat,
    const unsigned short* __restrict__ WoT,
    const float* __restrict__ bo, const float* __restrict__ x, float* __restrict__ out) {
  const int pix0 = blockIdx.x * 64;
  const int wave = threadIdx.x >> 6, lane = threadIdx.x & 63, l = lane & 15, qd = lane >> 4;
  const int base = pix0 + wave * 16;
  const int row = base + l;
  const float den = lstat[row] + lstat[32768 + row] + lstat[65536 + row] + lstat[98304 + row];
  const float inv = 1.f / den;
  short8 af[4];
#pragma unroll
  for (int kc = 0; kc < 4; ++kc) {
    float o[8] = {0.f, 0.f, 0.f, 0.f, 0.f, 0.f, 0.f, 0.f};
#pragma unroll
    for (int s = 0; s < 4; ++s) {
      uint4 v = *(const uint4*)(opart + ((size_t)s * 32768 + row) * 128 + kc * 32 + qd * 8);
      unsigned int uu[4] = {v.x, v.y, v.z, v.w};
#pragma unroll
      for (int j = 0; j < 4; ++j) {
        o[2 * j]     += bf2f((unsigned short)(uu[j] & 0xffff));
        o[2 * j + 1] += bf2f((unsigned short)(uu[j] >> 16));
      }
    }
    union { unsigned int u[4]; short8 v8; } pk;
#pragma unroll
    for (int j = 0; j < 4; ++j) pk.u[j] = cvtpk(o[2 * j] * inv, o[2 * j + 1] * inv);
    af[kc] = pk.v8;
  }
#pragma unroll
  for (int sub = 0; sub < 16; ++sub) {
    const int c0 = sub * 16 + 4 * qd;
    float4 bb = *(const float4*)(bo + c0);
    f32x4 acc = (f32x4){bb.x, bb.y, bb.z, bb.w};
#pragma unroll
    for (int kc = 0; kc < 4; ++kc) {
      short8 wf = ld8(WoT + (size_t)(sub * 16 + l) * 128 + kc * 32 + qd * 8);
      acc = MFMA(wf, af[kc], acc);   // D[c][pixel]
    }
    float4 xv = *(const float4*)(x + (size_t)row * 256 + c0);
    float4 res;
    res.x = acc[0] + xv.x;
    res.y = acc[1] + xv.y;
    res.z = acc[2] + xv.z;
    res.w = acc[3] + xv.w;
    *(float4*)(out + (size_t)row * 256 + c0) = res;
  }
}

// ---------------------------------------------------------------------------
extern "C" void kernel_launch(void* const* d_in, const int* in_sizes, int n_in,
                              void* d_out, int out_size, void* d_ws, size_t ws_size,
                              hipStream_t stream) {
  const float* x  = (const float*)d_in[0];
  const float* Wq = (const float*)d_in[1];
  const float* bq = (const float*)d_in[2];
  const float* Wk = (const float*)d_in[3];
  const float* bk = (const float*)d_in[4];
  const float* Wv = (const float*)d_in[5];
  const float* bv = (const float*)d_in[6];
  const float* Wo = (const float*)d_in[7];
  const float* bo = (const float*)d_in[8];

  char* ws = (char*)d_ws;
  // Workspace map (bytes):
  //   qh    @ 0          2 MB   fp16 [32768][32]
  //   KVF   @ 2 MB       10 MB  fused kh(fp16)|V(bf16) frags
  //   Wth   @ 12 MB      96 KB
  //   Wtl   @ +96 KB     96 KB
  //   WoT   @ +192 KB    64 KB
  //   lst   @ +256 KB    512 KB [4][32768]
  //   ao    @ 13,369,344 8 MB   (fallback path only)
  //   opart @ 16 MB      32 MB  (fused path only; needs ws >= 48 MB)
  unsigned short* qh  = (unsigned short*)(ws + 0);
  unsigned short* KVF = (unsigned short*)(ws + 2097152);
  unsigned short* Wth = (unsigned short*)(ws + 12582912);
  unsigned short* Wtl = (unsigned short*)(ws + 12681216);
  unsigned short* WoT = (unsigned short*)(ws + 12779520);
  float*          lst = (float*)(ws + 12845056);
  unsigned short* ao  = (unsigned short*)(ws + 13369344);

  const bool fused = (ws_size >= 50331648ull);  // 48 MB for opart@16MB+32MB
  unsigned short* opart = fused ? (unsigned short*)(ws + 16777216)
                                : (unsigned short*)d_out;

  prep_weights<<<320, 256, 0, stream>>>(Wq, Wk, Wv, Wo, Wth, Wtl, WoT);
  proj_qkv<<<1024, 256, 0, stream>>>(x, Wth, Wtl, bq, bk, bv, qh, KVF);
  flash_attn<<<1024, 256, 0, stream>>>(qh, KVF, opart, lst);
  if (fused) {
    combine_out<<<512, 256, 0, stream>>>(opart, lst, WoT, bo, x, (float*)d_out);
  } else {
    combine_splits<<<2048, 256, 0, stream>>>(opart, lst, ao);
    out_proj<<<512, 256, 0, stream>>>(ao, WoT, bo, x, (float*)d_out);
  }
}

// Round 13
// 207.828 us; speedup vs baseline: 1.0133x; 1.0133x over previous
//
#include <hip/hip_runtime.h>

typedef __attribute__((ext_vector_type(8))) short short8;
typedef __attribute__((ext_vector_type(8))) _Float16 half8;
typedef __attribute__((ext_vector_type(2))) float f32x2;
typedef __attribute__((ext_vector_type(4))) float f32x4;
typedef __attribute__((ext_vector_type(16))) float f32x16;

__device__ __forceinline__ unsigned short f2bf(float f) {
  unsigned int u = __float_as_uint(f);
  u += 0x7fffu + ((u >> 16) & 1u);   // round-to-nearest-even
  return (unsigned short)(u >> 16);
}
__device__ __forceinline__ float bf2f(unsigned short h) {
  return __uint_as_float(((unsigned int)h) << 16);
}
// HW packed f32->bf16 (RNE): 1 instr (low=a, high=b)
__device__ __forceinline__ unsigned int cvtpk(float a, float b) {
  unsigned int r;
  asm("v_cvt_pk_bf16_f32 %0, %1, %2" : "=v"(r) : "v"(a), "v"(b));
  return r;
}
// f32 -> fp16 bits (RNE)
__device__ __forceinline__ unsigned short f2h(float f) {
  unsigned int r;
  asm("v_cvt_f16_f32 %0, %1" : "=v"(r) : "v"(f));
  return (unsigned short)r;
}
__device__ __forceinline__ float lo16f(unsigned int u) { return __uint_as_float(u << 16); }
__device__ __forceinline__ float hi16f(unsigned int u) { return __uint_as_float(u & 0xffff0000u); }
__device__ __forceinline__ short8 ld8(const unsigned short* p) {
  return *(const short8*)p;
}
__device__ __forceinline__ half8 ld8h(const unsigned short* p) {
  return *(const half8*)p;
}
__device__ __forceinline__ int swap23(int x) {  // swap bits 2<->3
  return (x & 0x13) | ((x & 4) << 1) | ((x & 8) >> 1);
}
#define MFMA(a, b, c) __builtin_amdgcn_mfma_f32_16x16x32_bf16((a), (b), (c), 0, 0, 0)
#define MFMA32(a, b, c) __builtin_amdgcn_mfma_f32_32x32x16_bf16((a), (b), (c), 0, 0, 0)
#define MFMA32H(a, b, c) __builtin_amdgcn_mfma_f32_32x32x16_f16((a), (b), (c), 0, 0, 0)
#define LOG2E 1.4426950408889634f

// ---------------------------------------------------------------------------
// Kernel 1: weight prep. Wcat^T hi/lo bf16 [192][256] (rows 0-31 Wq^T, 32-63
// Wk^T, 64-191 Wv^T), WoT bf16 [256][128].
// ---------------------------------------------------------------------------
__global__ void prep_weights(const float* __restrict__ Wq, const float* __restrict__ Wk,
                             const float* __restrict__ Wv, const float* __restrict__ Wo,
                             unsigned short* __restrict__ Wth, unsigned short* __restrict__ Wtl,
                             unsigned short* __restrict__ WoT) {
  int idx = blockIdx.x * 256 + threadIdx.x;
  if (idx < 192 * 256) {
    int o = idx >> 8, c = idx & 255;
    float w = (o < 32) ? Wq[c * 32 + o] : (o < 64) ? Wk[c * 32 + (o - 32)] : Wv[c * 128 + (o - 64)];
    unsigned short h = f2bf(w);
    Wth[idx] = h;
    Wtl[idx] = f2bf(w - bf2f(h));
  } else if (idx < 192 * 256 + 256 * 128) {
    int j = idx - 192 * 256;
    int c = j >> 7, d = j & 127;
    WoT[j] = f2bf(Wo[d * 256 + c]);
  }
}

// ---------------------------------------------------------------------------
// Kernel 2: QKV projection (R12 layout, measured good). 32 pixels/block.
// Vectorized 8B stores via per-branch MFMA operand order:
//   q/k: D[outc][pixel]; V: D[pixel][dv].
// KVF fused fragment-major buffer, 20KB per nt-tile:
//   KVF[b*64+nt] : [0,2048)    kh fp16 frags [kt(2)][step(2)][lane(64)][e(8)]
//                  [2048,10240) V bf16 frags [dt(4)][ks(4)][lane(64)][e(8)]
// ---------------------------------------------------------------------------
__global__ __launch_bounds__(256) void proj_qkv(
    const float* __restrict__ x,
    const unsigned short* __restrict__ Wth, const unsigned short* __restrict__ Wtl,
    const float* __restrict__ bq, const float* __restrict__ bk, const float* __restrict__ bv,
    unsigned short* __restrict__ qh, unsigned short* __restrict__ KVF) {
  __shared__ unsigned short xsh[32][264];
  __shared__ unsigned short xsl[32][264];
  const int pix0 = blockIdx.x * 32;
  const int b = pix0 >> 12;
  const int nloc0 = pix0 & 4095;
  const int tid = threadIdx.x;

#pragma unroll
  for (int i = 0; i < 8; ++i) {
    int chunk = i * 256 + tid;
    int row = chunk >> 6;
    int c4 = (chunk & 63) * 4;
    float4 v = *(const float4*)(x + (size_t)(pix0 + row) * 256 + c4);
    unsigned int h01 = cvtpk(v.x, v.y), h23 = cvtpk(v.z, v.w);
    unsigned int l01 = cvtpk(v.x - lo16f(h01), v.y - hi16f(h01));
    unsigned int l23 = cvtpk(v.z - lo16f(h23), v.w - hi16f(h23));
    uint2 hp, lp;
    hp.x = h01; hp.y = h23;
    lp.x = l01; lp.y = l23;
    *(uint2*)&xsh[row][c4] = hp;
    *(uint2*)&xsl[row][c4] = lp;
  }
  __syncthreads();

  const int wave = tid >> 6, lane = tid & 63, l = lane & 15, qd = lane >> 4;
  // Block-constant fragment geometry (nloc0 is a multiple of 32):
  const int nt = nloc0 >> 6;
  const int ktc = (nloc0 >> 5) & 1;       // k-frag kt
  const int ksbase = (nloc0 >> 4) & 2;    // v-frag ks base
  const int hh = qd >> 1;
  const int eb = 4 * (qd & 1);

#pragma unroll
  for (int si = 0; si < 3; ++si) {
    const int sub = wave + si * 4;
    const int outc0 = sub * 16;
    if (si == 0) {  // q/k: D[outc][pixel], split-x precision, fp16 output
      const float* bp = (outc0 < 32) ? (bq + outc0) : (bk + outc0 - 32);
      const float4 bb = *(const float4*)(bp + 4 * qd);
      f32x4 acc[2];
      acc[0] = (f32x4){bb.x, bb.y, bb.z, bb.w};
      acc[1] = (f32x4){bb.x, bb.y, bb.z, bb.w};
#pragma unroll
      for (int kc = 0; kc < 8; ++kc) {
        short8 whf = ld8(Wth + (size_t)(outc0 + l) * 256 + kc * 32 + qd * 8);
        short8 wlf = ld8(Wtl + (size_t)(outc0 + l) * 256 + kc * 32 + qd * 8);
#pragma unroll
        for (int m = 0; m < 2; ++m) {
          short8 xhf = ld8(&xsh[m * 16 + l][kc * 32 + qd * 8]);
          short8 xlf = ld8(&xsl[m * 16 + l][kc * 32 + qd * 8]);
          acc[m] = MFMA(wlf, xhf, acc[m]);   // w_lo * x_hi
          acc[m] = MFMA(whf, xlf, acc[m]);   // w_hi * x_lo
          acc[m] = MFMA(whf, xhf, acc[m]);   // w_hi * x_hi
        }
      }
      if (outc0 < 32) {  // q: lane holds outc0+4qd+r for pixel pix0+m*16+l
#pragma unroll
        for (int m = 0; m < 2; ++m) {
          const size_t pixel = (size_t)pix0 + m * 16 + l;
          uint2 st;
          st.x = (unsigned int)f2h(acc[m][0] * LOG2E) |
                 ((unsigned int)f2h(acc[m][1] * LOG2E) << 16);
          st.y = (unsigned int)f2h(acc[m][2] * LOG2E) |
                 ((unsigned int)f2h(acc[m][3] * LOG2E) << 16);
          *(uint2*)(qh + pixel * 32 + outc0 + 4 * qd) = st;
        }
      } else {  // k: kd = (outc0-32)+4qd+r -> step fixed, e run of 4
        const int step = (outc0 - 32) >> 4;
#pragma unroll
        for (int m = 0; m < 2; ++m) {
          const int lpos = swap23(m * 16 + l);
          const size_t koff = (size_t)(b * 64 + nt) * 10240 +
                              (ktc * 2 + step) * 512 + (hh * 32 + lpos) * 8 + eb;
          uint2 st;
          st.x = (unsigned int)f2h(acc[m][0]) | ((unsigned int)f2h(acc[m][1]) << 16);
          st.y = (unsigned int)f2h(acc[m][2]) | ((unsigned int)f2h(acc[m][3]) << 16);
          *(uint2*)(KVF + koff) = st;
        }
      }
    } else {  // v: D[pixel][dv] -> lane holds 4 consecutive pixels for dv=dv0+l
      const int dv = (outc0 - 64) + l;
      const float bias = bv[dv];
      f32x4 acc[2];
      acc[0] = (f32x4){bias, bias, bias, bias};
      acc[1] = (f32x4){bias, bias, bias, bias};
#pragma unroll
      for (int kc = 0; kc < 8; ++kc) {
        short8 whf = ld8(Wth + (size_t)(outc0 + l) * 256 + kc * 32 + qd * 8);
#pragma unroll
        for (int m = 0; m < 2; ++m) {
          short8 xhf = ld8(&xsh[m * 16 + l][kc * 32 + qd * 8]);
          acc[m] = MFMA(xhf, whf, acc[m]);  // D = x * Wv
        }
      }
      const int dt = dv >> 5, lam = dv & 31;
#pragma unroll
      for (int m = 0; m < 2; ++m) {
        const int ks = ksbase + m;
        const size_t voff = (size_t)(b * 64 + nt) * 10240 + 2048 +
                            (dt * 4 + ks) * 512 + (hh * 32 + lam) * 8 + eb;
        uint2 st;
        st.x = cvtpk(acc[m][0], acc[m][1]);
        st.y = cvtpk(acc[m][2], acc[m][3]);
        *(uint2*)(KVF + voff) = st;
      }
    }
  }
}

// ---------------------------------------------------------------------------
// Kernel 3: flash attention. R16: BARRIER-FREE, direct-from-L2 K/V reads.
// Six structural experiments (R9-R14, all 53-56us) shared one element: the
// barrier-synced LDS staging round. Per-pipe sums say ~80% of issue slots are
// empty with no single pipe saturated — the invariant is the synchronized
// round structure. KVF is fragment-major (every fragment read is a contiguous
// coalesced 1KB burst) and L2-resident (FETCH=6.2MB), so the LDS hop is not
// needed for coalescing (it was co-introduced with fragment-major in R7,
// never ablated alone). This kernel deletes LDS/double-buffer/all
// __syncthreads: waves are fully independent streams; compiler batches each
// section's loads with no barrier fence. Cost: 4x L2 read amplification
// (160KB/iter/CU ~ 2.9k cyc at ~56B/cyc L2 BW = ~19us floor, well under
// 54us). R12's 2-tile/2-wave shape retained (K/V reads amortized over 64 q).
// exp2 back to hardware v_exp (R15's poly = spill regression; trans is
// quarter-rate per-SIMD, never the wall).
// ---------------------------------------------------------------------------
__global__ __launch_bounds__(256, 2) void flash_attn(
    const unsigned short* __restrict__ qh,
    const unsigned short* __restrict__ KVF, unsigned short* __restrict__ opart,
    float* __restrict__ lstat) {
  const int b = blockIdx.x & 7;
  const int r7 = blockIdx.x >> 3;      // 0..63
  const int tile = r7 & 15;            // 0..15 (256-query tiles)
  const int split = r7 >> 4;           // 0..3
  const int wave = threadIdx.x >> 6;
  const int lane = threadIdx.x & 63;
  const int lam = lane & 31;           // query index within 32-tile
  const int h = lane >> 5;             // half-wave
  const int m0 = tile * 256 + wave * 64;
  const int nt0 = split * 16;

  const unsigned short* qh_b = qh + (size_t)b * 4096 * 32;
  const unsigned short* kv_b = KVF + (size_t)b * 64 * 10240;

  // Q B-frags (persistent, fp16), 2 tiles: B[k=dim 16*step+8h+j][n=query lam]
  half8 qf[2][2];
#pragma unroll
  for (int t = 0; t < 2; ++t)
#pragma unroll
    for (int step = 0; step < 2; ++step)
      qf[t][step] = ld8h(qh_b + (size_t)(m0 + t * 32 + lam) * 32 + step * 16 + h * 8);

  f32x16 acc0[4], acc1[4];
#pragma unroll
  for (int dt = 0; dt < 4; ++dt)
#pragma unroll
    for (int e = 0; e < 16; ++e) { acc0[dt][e] = 0.f; acc1[dt][e] = 0.f; }
  f32x2 lr0 = (f32x2){0.f, 0.f}, lr1 = (f32x2){0.f, 0.f};

#pragma unroll 1
  for (int it = 0; it < 16; ++it) {
    const unsigned short* cb = kv_b + (size_t)(nt0 + it) * 10240;

    // ===== kt = 0: QK =====
    half8 k0a = ld8h(cb + 0 * 512 + lane * 8);
    half8 k0b = ld8h(cb + 1 * 512 + lane * 8);
    f32x16 z0, z1;
#pragma unroll
    for (int e = 0; e < 16; ++e) { z0[e] = 0.f; z1[e] = 0.f; }
    __builtin_amdgcn_s_setprio(1);
    z0 = MFMA32H(k0a, qf[0][0], z0);
    z0 = MFMA32H(k0b, qf[0][1], z0);
    z1 = MFMA32H(k0a, qf[1][0], z1);
    z1 = MFMA32H(k0b, qf[1][1], z1);
    __builtin_amdgcn_s_setprio(0);
    // exp2 + pack (kt=0)
    unsigned int ppA0[8], ppA1[8];
#pragma unroll
    for (int g = 0; g < 8; ++g) {
      float a0 = __builtin_amdgcn_exp2f(z0[2 * g]);
      float a1 = __builtin_amdgcn_exp2f(z0[2 * g + 1]);
      lr0 += (f32x2){a0, a1};
      ppA0[g] = cvtpk(a0, a1);
      float c0 = __builtin_amdgcn_exp2f(z1[2 * g]);
      float c1 = __builtin_amdgcn_exp2f(z1[2 * g + 1]);
      lr1 += (f32x2){c0, c1};
      ppA1[g] = cvtpk(c0, c1);
    }

    // ===== kt = 1 QK + PV(kt=0) in one MFMA burst =====
    half8 k1a = ld8h(cb + 2 * 512 + lane * 8);
    half8 k1b = ld8h(cb + 3 * 512 + lane * 8);
    f32x16 w0, w1;
#pragma unroll
    for (int e = 0; e < 16; ++e) { w0[e] = 0.f; w1[e] = 0.f; }
    __builtin_amdgcn_s_setprio(1);
    w0 = MFMA32H(k1a, qf[0][0], w0);
    w0 = MFMA32H(k1b, qf[0][1], w0);
    w1 = MFMA32H(k1a, qf[1][0], w1);
    w1 = MFMA32H(k1b, qf[1][1], w1);
#pragma unroll
    for (int kss = 0; kss < 2; ++kss) {   // ks = 0,1
      union { unsigned int u[4]; short8 v; } pf0, pf1;
#pragma unroll
      for (int j = 0; j < 4; ++j) { pf0.u[j] = ppA0[4 * kss + j]; pf1.u[j] = ppA1[4 * kss + j]; }
#pragma unroll
      for (int dt = 0; dt < 4; ++dt) {
        short8 vfrag = ld8(cb + 2048 + (dt * 4 + kss) * 512 + lane * 8);
        acc0[dt] = MFMA32(vfrag, pf0.v, acc0[dt]);
        acc1[dt] = MFMA32(vfrag, pf1.v, acc1[dt]);
      }
    }
    __builtin_amdgcn_s_setprio(0);
    // exp2 + pack (kt=1)
    unsigned int ppB0[8], ppB1[8];
#pragma unroll
    for (int g = 0; g < 8; ++g) {
      float a0 = __builtin_amdgcn_exp2f(w0[2 * g]);
      float a1 = __builtin_amdgcn_exp2f(w0[2 * g + 1]);
      lr0 += (f32x2){a0, a1};
      ppB0[g] = cvtpk(a0, a1);
      float c0 = __builtin_amdgcn_exp2f(w1[2 * g]);
      float c1 = __builtin_amdgcn_exp2f(w1[2 * g + 1]);
      lr1 += (f32x2){c0, c1};
      ppB1[g] = cvtpk(c0, c1);
    }
    // ===== PV(kt=1) =====
    __builtin_amdgcn_s_setprio(1);
#pragma unroll
    for (int kss = 0; kss < 2; ++kss) {   // ks = 2,3
      union { unsigned int u[4]; short8 v; } pf0, pf1;
#pragma unroll
      for (int j = 0; j < 4; ++j) { pf0.u[j] = ppB0[4 * kss + j]; pf1.u[j] = ppB1[4 * kss + j]; }
#pragma unroll
      for (int dt = 0; dt < 4; ++dt) {
        short8 vfrag = ld8(cb + 2048 + (dt * 4 + 2 + kss) * 512 + lane * 8);
        acc0[dt] = MFMA32(vfrag, pf0.v, acc0[dt]);
        acc1[dt] = MFMA32(vfrag, pf1.v, acc1[dt]);
      }
    }
    __builtin_amdgcn_s_setprio(0);
  }

  // Epilogue per tile: combine l across half-waves, store unnormalized partials.
  {
    const float lrun = lr0.x + lr0.y;
    const float ltot = lrun + __shfl_xor(lrun, 32);
    const int grow = b * 4096 + m0 + lam;
    if (h == 0) lstat[split * 32768 + grow] = ltot;
    const size_t obase = ((size_t)split * 32768 + grow) * 128;
#pragma unroll
    for (int dt = 0; dt < 4; ++dt)
#pragma unroll
      for (int g = 0; g < 8; ++g) {
        int r = 2 * g;
        int dv = dt * 32 + (r & 3) + 8 * (r >> 2) + 4 * h;
        *(unsigned int*)(opart + obase + dv) = cvtpk(acc0[dt][r], acc0[dt][r + 1]);
      }
  }
  {
    const float lrun = lr1.x + lr1.y;
    const float ltot = lrun + __shfl_xor(lrun, 32);
    const int grow = b * 4096 + m0 + 32 + lam;
    if (h == 0) lstat[split * 32768 + grow] = ltot;
    const size_t obase = ((size_t)split * 32768 + grow) * 128;
#pragma unroll
    for (int dt = 0; dt < 4; ++dt)
#pragma unroll
      for (int g = 0; g < 8; ++g) {
        int r = 2 * g;
        int dv = dt * 32 + (r & 3) + 8 * (r >> 2) + 4 * h;
        *(unsigned int*)(opart + obase + dv) = cvtpk(acc1[dt][r], acc1[dt][r + 1]);
      }
  }
}

// ---------------------------------------------------------------------------
// Kernel 3b (fallback path): combine split-K partials -> ao (bf16).
// ---------------------------------------------------------------------------
__global__ __launch_bounds__(256) void combine_splits(
    const unsigned short* __restrict__ opart, const float* __restrict__ lstat,
    unsigned short* __restrict__ ao) {
  const int tid = threadIdx.x;
  const int row = blockIdx.x * 16 + (tid >> 4);
  const int col = (tid & 15) * 8;
  float den = lstat[row] + lstat[32768 + row] + lstat[65536 + row] + lstat[98304 + row];
  float inv = 1.f / den;
  float o[8] = {0.f, 0.f, 0.f, 0.f, 0.f, 0.f, 0.f, 0.f};
#pragma unroll
  for (int s = 0; s < 4; ++s) {
    uint4 v = *(const uint4*)(opart + ((size_t)s * 32768 + row) * 128 + col);
    unsigned int uu[4] = {v.x, v.y, v.z, v.w};
#pragma unroll
    for (int j = 0; j < 4; ++j) {
      o[2 * j]     += bf2f((unsigned short)(uu[j] & 0xffff));
      o[2 * j + 1] += bf2f((unsigned short)(uu[j] >> 16));
    }
  }
  uint4 outv;
  outv.x = cvtpk(o[0] * inv, o[1] * inv);
  outv.y = cvtpk(o[2] * inv, o[3] * inv);
  outv.z = cvtpk(o[4] * inv, o[5] * inv);
  outv.w = cvtpk(o[6] * inv, o[7] * inv);
  *(uint4*)(ao + (size_t)row * 128 + col) = outv;
}

// ---------------------------------------------------------------------------
// Kernel 4 (fallback path): output projection + bias + residual.
// ---------------------------------------------------------------------------
__global__ __launch_bounds__(256) void out_proj(
    const unsigned short* __restrict__ ao, const unsigned short* __restrict__ WoT,
    const float* __restrict__ bo, const float* __restrict__ x, float* __restrict__ out) {
  const int pix0 = blockIdx.x * 64;
  const int wave = threadIdx.x >> 6, lane = threadIdx.x & 63, l = lane & 15, qd = lane >> 4;
  const int base = pix0 + wave * 16;
  short8 af[4];
#pragma unroll
  for (int kc = 0; kc < 4; ++kc)
    af[kc] = ld8(ao + (size_t)(base + l) * 128 + kc * 32 + qd * 8);
#pragma unroll
  for (int sub = 0; sub < 16; ++sub) {
    const int c0 = sub * 16 + 4 * qd;
    float4 bb = *(const float4*)(bo + c0);
    f32x4 acc = (f32x4){bb.x, bb.y, bb.z, bb.w};
#pragma unroll
    for (int kc = 0; kc < 4; ++kc) {
      short8 wf = ld8(WoT + (size_t)(sub * 16 + l) * 128 + kc * 32 + qd * 8);
      acc = MFMA(wf, af[kc], acc);   // D[c][pixel]
    }
    float4 xv = *(const float4*)(x + (size_t)(base + l) * 256 + c0);
    float4 res;
    res.x = acc[0] + xv.x;
    res.y = acc[1] + xv.y;
    res.z = acc[2] + xv.z;
    res.w = acc[3] + xv.w;
    *(float4*)(out + (size_t)(base + l) * 256 + c0) = res;
  }
}

// ---------------------------------------------------------------------------
// Kernel 4f (fused path): combine + output projection in ONE kernel.
// opart lives in WORKSPACE (no aliasing with the d_out output write).
// ---------------------------------------------------------------------------
__global__ __launch_bounds__(256) void combine_out(
    const unsigned short* __restrict__ opart, const float* __restrict__ lstat,
    const unsigned short* __restrict__ WoT,
    const float* __restrict__ bo, const float* __restrict__ x, float* __restrict__ out) {
  const int pix0 = blockIdx.x * 64;
  const int wave = threadIdx.x >> 6, lane = threadIdx.x & 63, l = lane & 15, qd = lane >> 4;
  const int base = pix0 + wave * 16;
  const int row = base + l;
  const float den = lstat[row] + lstat[32768 + row] + lstat[65536 + row] + lstat[98304 + row];
  const float inv = 1.f / den;
  short8 af[4];
#pragma unroll
  for (int kc = 0; kc < 4; ++kc) {
    float o[8] = {0.f, 0.f, 0.f, 0.f, 0.f, 0.f, 0.f, 0.f};
#pragma unroll
    for (int s = 0; s < 4; ++s) {
      uint4 v = *(const uint4*)(opart + ((size_t)s * 32768 + row) * 128 + kc * 32 + qd * 8);
      unsigned int uu[4] = {v.x, v.y, v.z, v.w};
#pragma unroll
      for (int j = 0; j < 4; ++j) {
        o[2 * j]     += bf2f((unsigned short)(uu[j] & 0xffff));
        o[2 * j + 1] += bf2f((unsigned short)(uu[j] >> 16));
      }
    }
    union { unsigned int u[4]; short8 v8; } pk;
#pragma unroll
    for (int j = 0; j < 4; ++j) pk.u[j] = cvtpk(o[2 * j] * inv, o[2 * j + 1] * inv);
    af[kc] = pk.v8;
  }
#pragma unroll
  for (int sub = 0; sub < 16; ++sub) {
    const int c0 = sub * 16 + 4 * qd;
    float4 bb = *(const float4*)(bo + c0);
    f32x4 acc = (f32x4){bb.x, bb.y, bb.z, bb.w};
#pragma unroll
    for (int kc = 0; kc < 4; ++kc) {
      short8 wf = ld8(WoT + (size_t)(sub * 16 + l) * 128 + kc * 32 + qd * 8);
      acc = MFMA(wf, af[kc], acc);   // D[c][pixel]
    }
    float4 xv = *(const float4*)(x + (size_t)row * 256 + c0);
    float4 res;
    res.x = acc[0] + xv.x;
    res.y = acc[1] + xv.y;
    res.z = acc[2] + xv.z;
    res.w = acc[3] + xv.w;
    *(float4*)(out + (size_t)row * 256 + c0) = res;
  }
}

// ---------------------------------------------------------------------------
extern "C" void kernel_launch(void* const* d_in, const int* in_sizes, int n_in,
                              void* d_out, int out_size, void* d_ws, size_t ws_size,
                              hipStream_t stream) {
  const float* x  = (const float*)d_in[0];
  const float* Wq = (const float*)d_in[1];
  const float* bq = (const float*)d_in[2];
  const float* Wk = (const float*)d_in[3];
  const float* bk = (const float*)d_in[4];
  const float* Wv = (const float*)d_in[5];
  const float* bv = (const float*)d_in[6];
  const float* Wo = (const float*)d_in[7];
  const float* bo = (const float*)d_in[8];

  char* ws = (char*)d_ws;
  // Workspace map (bytes):
  //   qh    @ 0          2 MB   fp16 [32768][32]
  //   KVF   @ 2 MB       10 MB  fused kh(fp16)|V(bf16) frags
  //   Wth   @ 12 MB      96 KB
  //   Wtl   @ +96 KB     96 KB
  //   WoT   @ +192 KB    64 KB
  //   lst   @ +256 KB    512 KB [4][32768]
  //   ao    @ 13,369,344 8 MB   (fallback path only)
  //   opart @ 16 MB      32 MB  (fused path only; needs ws >= 48 MB)
  unsigned short* qh  = (unsigned short*)(ws + 0);
  unsigned short* KVF = (unsigned short*)(ws + 2097152);
  unsigned short* Wth = (unsigned short*)(ws + 12582912);
  unsigned short* Wtl = (unsigned short*)(ws + 12681216);
  unsigned short* WoT = (unsigned short*)(ws + 12779520);
  float*          lst = (float*)(ws + 12845056);
  unsigned short* ao  = (unsigned short*)(ws + 13369344);

  const bool fused = (ws_size >= 50331648ull);  // 48 MB for opart@16MB+32MB
  unsigned short* opart = fused ? (unsigned short*)(ws + 16777216)
                                : (unsigned short*)d_out;

  prep_weights<<<320, 256, 0, stream>>>(Wq, Wk, Wv, Wo, Wth, Wtl, WoT);
  proj_qkv<<<1024, 256, 0, stream>>>(x, Wth, Wtl, bq, bk, bv, qh, KVF);
  flash_attn<<<512, 256, 0, stream>>>(qh, KVF, opart, lst);
  if (fused) {
    combine_out<<<512, 256, 0, stream>>>(opart, lst, WoT, bo, x, (float*)d_out);
  } else {
    combine_splits<<<2048, 256, 0, stream>>>(opart, lst, ao);
    out_proj<<<512, 256, 0, stream>>>(ao, WoT, bo, x, (float*)d_out);
  }
}

// Round 14
// 182.214 us; speedup vs baseline: 1.1558x; 1.1406x over previous
//
#include <hip/hip_runtime.h>

typedef __attribute__((ext_vector_type(8))) short short8;
typedef __attribute__((ext_vector_type(8))) _Float16 half8;
typedef __attribute__((ext_vector_type(2))) float f32x2;
typedef __attribute__((ext_vector_type(4))) float f32x4;
typedef __attribute__((ext_vector_type(16))) float f32x16;

__device__ __forceinline__ unsigned short f2bf(float f) {
  unsigned int u = __float_as_uint(f);
  u += 0x7fffu + ((u >> 16) & 1u);   // round-to-nearest-even
  return (unsigned short)(u >> 16);
}
__device__ __forceinline__ float bf2f(unsigned short h) {
  return __uint_as_float(((unsigned int)h) << 16);
}
// HW packed f32->bf16 (RNE): 1 instr (low=a, high=b)
__device__ __forceinline__ unsigned int cvtpk(float a, float b) {
  unsigned int r;
  asm("v_cvt_pk_bf16_f32 %0, %1, %2" : "=v"(r) : "v"(a), "v"(b));
  return r;
}
// f32 -> fp16 bits (RNE)
__device__ __forceinline__ unsigned short f2h(float f) {
  unsigned int r;
  asm("v_cvt_f16_f32 %0, %1" : "=v"(r) : "v"(f));
  return (unsigned short)r;
}
__device__ __forceinline__ float lo16f(unsigned int u) { return __uint_as_float(u << 16); }
__device__ __forceinline__ float hi16f(unsigned int u) { return __uint_as_float(u & 0xffff0000u); }
__device__ __forceinline__ short8 ld8(const unsigned short* p) {
  return *(const short8*)p;
}
__device__ __forceinline__ half8 ld8h(const unsigned short* p) {
  return *(const half8*)p;
}
__device__ __forceinline__ int swap23(int x) {  // swap bits 2<->3
  return (x & 0x13) | ((x & 4) << 1) | ((x & 8) >> 1);
}
#define MFMA(a, b, c) __builtin_amdgcn_mfma_f32_16x16x32_bf16((a), (b), (c), 0, 0, 0)
#define MFMA32(a, b, c) __builtin_amdgcn_mfma_f32_32x32x16_bf16((a), (b), (c), 0, 0, 0)
#define MFMA32H(a, b, c) __builtin_amdgcn_mfma_f32_32x32x16_f16((a), (b), (c), 0, 0, 0)
#define LOG2E 1.4426950408889634f

typedef const __attribute__((address_space(1))) unsigned int* gas_u32p;
typedef __attribute__((address_space(3))) unsigned int* las_u32p;

// ---------------------------------------------------------------------------
// Kernel 1: weight prep. Wcat^T hi/lo bf16 [192][256] (rows 0-31 Wq^T, 32-63
// Wk^T, 64-191 Wv^T), WoT bf16 [256][128].
// ---------------------------------------------------------------------------
__global__ void prep_weights(const float* __restrict__ Wq, const float* __restrict__ Wk,
                             const float* __restrict__ Wv, const float* __restrict__ Wo,
                             unsigned short* __restrict__ Wth, unsigned short* __restrict__ Wtl,
                             unsigned short* __restrict__ WoT) {
  int idx = blockIdx.x * 256 + threadIdx.x;
  if (idx < 192 * 256) {
    int o = idx >> 8, c = idx & 255;
    float w = (o < 32) ? Wq[c * 32 + o] : (o < 64) ? Wk[c * 32 + (o - 32)] : Wv[c * 128 + (o - 64)];
    unsigned short h = f2bf(w);
    Wth[idx] = h;
    Wtl[idx] = f2bf(w - bf2f(h));
  } else if (idx < 192 * 256 + 256 * 128) {
    int j = idx - 192 * 256;
    int c = j >> 7, d = j & 127;
    WoT[j] = f2bf(Wo[d * 256 + c]);
  }
}

// ---------------------------------------------------------------------------
// Kernel 2: QKV projection (R12 layout, measured good). 32 pixels/block.
// Vectorized 8B stores via per-branch MFMA operand order:
//   q/k: D[outc][pixel]; V: D[pixel][dv].
// KVF fused fragment-major buffer, 20KB per nt-tile:
//   KVF[b*64+nt] : [0,2048)    kh fp16 frags [kt(2)][step(2)][lane(64)][e(8)]
//                  [2048,10240) V bf16 frags [dt(4)][ks(4)][lane(64)][e(8)]
// ---------------------------------------------------------------------------
__global__ __launch_bounds__(256) void proj_qkv(
    const float* __restrict__ x,
    const unsigned short* __restrict__ Wth, const unsigned short* __restrict__ Wtl,
    const float* __restrict__ bq, const float* __restrict__ bk, const float* __restrict__ bv,
    unsigned short* __restrict__ qh, unsigned short* __restrict__ KVF) {
  __shared__ unsigned short xsh[32][264];
  __shared__ unsigned short xsl[32][264];
  const int pix0 = blockIdx.x * 32;
  const int b = pix0 >> 12;
  const int nloc0 = pix0 & 4095;
  const int tid = threadIdx.x;

#pragma unroll
  for (int i = 0; i < 8; ++i) {
    int chunk = i * 256 + tid;
    int row = chunk >> 6;
    int c4 = (chunk & 63) * 4;
    float4 v = *(const float4*)(x + (size_t)(pix0 + row) * 256 + c4);
    unsigned int h01 = cvtpk(v.x, v.y), h23 = cvtpk(v.z, v.w);
    unsigned int l01 = cvtpk(v.x - lo16f(h01), v.y - hi16f(h01));
    unsigned int l23 = cvtpk(v.z - lo16f(h23), v.w - hi16f(h23));
    uint2 hp, lp;
    hp.x = h01; hp.y = h23;
    lp.x = l01; lp.y = l23;
    *(uint2*)&xsh[row][c4] = hp;
    *(uint2*)&xsl[row][c4] = lp;
  }
  __syncthreads();

  const int wave = tid >> 6, lane = tid & 63, l = lane & 15, qd = lane >> 4;
  // Block-constant fragment geometry (nloc0 is a multiple of 32):
  const int nt = nloc0 >> 6;
  const int ktc = (nloc0 >> 5) & 1;       // k-frag kt
  const int ksbase = (nloc0 >> 4) & 2;    // v-frag ks base
  const int hh = qd >> 1;
  const int eb = 4 * (qd & 1);

#pragma unroll
  for (int si = 0; si < 3; ++si) {
    const int sub = wave + si * 4;
    const int outc0 = sub * 16;
    if (si == 0) {  // q/k: D[outc][pixel], split-x precision, fp16 output
      const float* bp = (outc0 < 32) ? (bq + outc0) : (bk + outc0 - 32);
      const float4 bb = *(const float4*)(bp + 4 * qd);
      f32x4 acc[2];
      acc[0] = (f32x4){bb.x, bb.y, bb.z, bb.w};
      acc[1] = (f32x4){bb.x, bb.y, bb.z, bb.w};
#pragma unroll
      for (int kc = 0; kc < 8; ++kc) {
        short8 whf = ld8(Wth + (size_t)(outc0 + l) * 256 + kc * 32 + qd * 8);
        short8 wlf = ld8(Wtl + (size_t)(outc0 + l) * 256 + kc * 32 + qd * 8);
#pragma unroll
        for (int m = 0; m < 2; ++m) {
          short8 xhf = ld8(&xsh[m * 16 + l][kc * 32 + qd * 8]);
          short8 xlf = ld8(&xsl[m * 16 + l][kc * 32 + qd * 8]);
          acc[m] = MFMA(wlf, xhf, acc[m]);   // w_lo * x_hi
          acc[m] = MFMA(whf, xlf, acc[m]);   // w_hi * x_lo
          acc[m] = MFMA(whf, xhf, acc[m]);   // w_hi * x_hi
        }
      }
      if (outc0 < 32) {  // q: lane holds outc0+4qd+r for pixel pix0+m*16+l
#pragma unroll
        for (int m = 0; m < 2; ++m) {
          const size_t pixel = (size_t)pix0 + m * 16 + l;
          uint2 st;
          st.x = (unsigned int)f2h(acc[m][0] * LOG2E) |
                 ((unsigned int)f2h(acc[m][1] * LOG2E) << 16);
          st.y = (unsigned int)f2h(acc[m][2] * LOG2E) |
                 ((unsigned int)f2h(acc[m][3] * LOG2E) << 16);
          *(uint2*)(qh + pixel * 32 + outc0 + 4 * qd) = st;
        }
      } else {  // k: kd = (outc0-32)+4qd+r -> step fixed, e run of 4
        const int step = (outc0 - 32) >> 4;
#pragma unroll
        for (int m = 0; m < 2; ++m) {
          const int lpos = swap23(m * 16 + l);
          const size_t koff = (size_t)(b * 64 + nt) * 10240 +
                              (ktc * 2 + step) * 512 + (hh * 32 + lpos) * 8 + eb;
          uint2 st;
          st.x = (unsigned int)f2h(acc[m][0]) | ((unsigned int)f2h(acc[m][1]) << 16);
          st.y = (unsigned int)f2h(acc[m][2]) | ((unsigned int)f2h(acc[m][3]) << 16);
          *(uint2*)(KVF + koff) = st;
        }
      }
    } else {  // v: D[pixel][dv] -> lane holds 4 consecutive pixels for dv=dv0+l
      const int dv = (outc0 - 64) + l;
      const float bias = bv[dv];
      f32x4 acc[2];
      acc[0] = (f32x4){bias, bias, bias, bias};
      acc[1] = (f32x4){bias, bias, bias, bias};
#pragma unroll
      for (int kc = 0; kc < 8; ++kc) {
        short8 whf = ld8(Wth + (size_t)(outc0 + l) * 256 + kc * 32 + qd * 8);
#pragma unroll
        for (int m = 0; m < 2; ++m) {
          short8 xhf = ld8(&xsh[m * 16 + l][kc * 32 + qd * 8]);
          acc[m] = MFMA(xhf, whf, acc[m]);  // D = x * Wv
        }
      }
      const int dt = dv >> 5, lam = dv & 31;
#pragma unroll
      for (int m = 0; m < 2; ++m) {
        const int ks = ksbase + m;
        const size_t voff = (size_t)(b * 64 + nt) * 10240 + 2048 +
                            (dt * 4 + ks) * 512 + (hh * 32 + lam) * 8 + eb;
        uint2 st;
        st.x = cvtpk(acc[m][0], acc[m][1]);
        st.y = cvtpk(acc[m][2], acc[m][3]);
        *(uint2*)(KVF + voff) = st;
      }
    }
  }
}

// ---------------------------------------------------------------------------
// Kernel 3: flash attention. R17: BATCHED fragment loads.
// Surviving theory after 8 experiments: exposed per-load LDS latency. In the
// 53us configs every V fragment is ds_read immediately before its MFMA, and
// R12's 252/256 regs left the compiler no room to hoist -> 16 loads x ~120cyc
// exposed serially ~ 2.2k cyc/wave-iter (finally closes the 4k budget).
// Explains R16's regression (L2 latency per load even worse) and R14's null
// (1-tile halves MFMAs per load, canceling added coverage). Fix: 1 q-tile/
// wave (the only shape with register room: vf[4][4]=64 VGPR + ~76 base + 64
// AGPR ~ 204 <= 256 @ 2 waves/SIMD) and ALL 20 fragment loads batched into
// register arrays at iteration top — one amortized ~360cyc window instead of
// 16 serial stalls. Split-K x2, 512 blocks = 2/CU, 32 iters/block. LDS dbuf +
// barriers kept (proven better than all alternatives).
// ---------------------------------------------------------------------------
__device__ __forceinline__ void stage_kv(const unsigned short* __restrict__ src,
                                         unsigned short* dst, int wave, int lane) {
#pragma unroll
  for (int i = 0; i < 5; ++i) {
    const int c = wave * 5 + i;  // 20 x 1KB chunks, linear copy
    __builtin_amdgcn_global_load_lds(
        (gas_u32p)(const void*)(src + c * 512 + lane * 8),
        (las_u32p)(void*)(dst + c * 512), 16, 0, 0);
  }
}

__global__ __launch_bounds__(256, 2) void flash_attn(
    const unsigned short* __restrict__ qh,
    const unsigned short* __restrict__ KVF, unsigned short* __restrict__ opart,
    float* __restrict__ lstat) {
  __shared__ unsigned short kv[2][10240];   // 2 x 20KB double buffer
  const int b = blockIdx.x & 7;
  const int r7 = blockIdx.x >> 3;      // 0..63
  const int tile = r7 & 31;            // 0..31 (128-query tiles)
  const int split = r7 >> 5;           // 0..1
  const int wave = threadIdx.x >> 6;
  const int lane = threadIdx.x & 63;
  const int lam = lane & 31;           // query index within 32-tile
  const int h = lane >> 5;             // half-wave
  const int m0 = tile * 128 + wave * 32;
  const int nt0 = split * 32;

  const unsigned short* qh_b = qh + (size_t)b * 4096 * 32;
  const unsigned short* kv_b = KVF + (size_t)b * 64 * 10240;

  // Q B-frags (persistent, fp16): B[k=dim 16*step+8h+j][n=query lam]
  half8 qf[2];
#pragma unroll
  for (int step = 0; step < 2; ++step)
    qf[step] = ld8h(qh_b + (size_t)(m0 + lam) * 32 + step * 16 + h * 8);

  f32x16 acc[4];
#pragma unroll
  for (int dt = 0; dt < 4; ++dt)
#pragma unroll
    for (int e = 0; e < 16; ++e) acc[dt][e] = 0.f;
  f32x2 lr = (f32x2){0.f, 0.f};

  stage_kv(kv_b + (size_t)nt0 * 10240, &kv[0][0], wave, lane);
  __syncthreads();

  int cur = 0;
#pragma unroll 1
  for (int it = 0; it < 32; ++it) {
    if (it < 31)   // prefetch next tile into the other buffer
      stage_kv(kv_b + (size_t)(nt0 + it + 1) * 10240, &kv[cur ^ 1][0], wave, lane);

    const unsigned short* cb = &kv[cur][0];

    // ===== BATCH-ISSUE all 20 fragment loads (amortize LDS latency) =====
    half8 kf[4];
#pragma unroll
    for (int j = 0; j < 4; ++j)
      kf[j] = ld8h(cb + j * 512 + lane * 8);
    short8 vf[4][4];
#pragma unroll
    for (int dt = 0; dt < 4; ++dt)
#pragma unroll
      for (int ks = 0; ks < 4; ++ks)
        vf[dt][ks] = ld8(cb + 2048 + (dt * 4 + ks) * 512 + lane * 8);

    // ===== kt = 0: QK =====
    f32x16 z;
#pragma unroll
    for (int e = 0; e < 16; ++e) z[e] = 0.f;
    __builtin_amdgcn_s_setprio(1);
    z = MFMA32H(kf[0], qf[0], z);
    z = MFMA32H(kf[1], qf[1], z);
    __builtin_amdgcn_s_setprio(0);
    // exp2 + pack (kt=0)
    unsigned int ppA[8];
#pragma unroll
    for (int g = 0; g < 8; ++g) {
      float a0 = __builtin_amdgcn_exp2f(z[2 * g]);
      float a1 = __builtin_amdgcn_exp2f(z[2 * g + 1]);
      lr += (f32x2){a0, a1};
      ppA[g] = cvtpk(a0, a1);
    }

    // ===== kt = 1 QK + PV(kt=0) in one MFMA burst =====
    f32x16 w;
#pragma unroll
    for (int e = 0; e < 16; ++e) w[e] = 0.f;
    __builtin_amdgcn_s_setprio(1);
    w = MFMA32H(kf[2], qf[0], w);
    w = MFMA32H(kf[3], qf[1], w);
#pragma unroll
    for (int kss = 0; kss < 2; ++kss) {   // ks = 0,1
      union { unsigned int u[4]; short8 v; } pf;
#pragma unroll
      for (int j = 0; j < 4; ++j) pf.u[j] = ppA[4 * kss + j];
#pragma unroll
      for (int dt = 0; dt < 4; ++dt)
        acc[dt] = MFMA32(vf[dt][kss], pf.v, acc[dt]);
    }
    __builtin_amdgcn_s_setprio(0);
    // exp2 + pack (kt=1)
    unsigned int ppB[8];
#pragma unroll
    for (int g = 0; g < 8; ++g) {
      float a0 = __builtin_amdgcn_exp2f(w[2 * g]);
      float a1 = __builtin_amdgcn_exp2f(w[2 * g + 1]);
      lr += (f32x2){a0, a1};
      ppB[g] = cvtpk(a0, a1);
    }
    // ===== PV(kt=1) =====
    __builtin_amdgcn_s_setprio(1);
#pragma unroll
    for (int kss = 0; kss < 2; ++kss) {   // ks = 2,3
      union { unsigned int u[4]; short8 v; } pf;
#pragma unroll
      for (int j = 0; j < 4; ++j) pf.u[j] = ppB[4 * kss + j];
#pragma unroll
      for (int dt = 0; dt < 4; ++dt)
        acc[dt] = MFMA32(vf[dt][2 + kss], pf.v, acc[dt]);
    }
    __builtin_amdgcn_s_setprio(0);

    __syncthreads();   // next-buffer staging landed; all waves done with cur
    cur ^= 1;
  }

  // Epilogue: combine l across half-waves, store unnormalized partials.
  const float lrun = lr.x + lr.y;
  const float ltot = lrun + __shfl_xor(lrun, 32);
  const int grow = b * 4096 + m0 + lam;
  if (h == 0) lstat[split * 32768 + grow] = ltot;
  const size_t obase = ((size_t)split * 32768 + grow) * 128;
#pragma unroll
  for (int dt = 0; dt < 4; ++dt)
#pragma unroll
    for (int g = 0; g < 8; ++g) {
      int r = 2 * g;
      int dv = dt * 32 + (r & 3) + 8 * (r >> 2) + 4 * h;
      *(unsigned int*)(opart + obase + dv) = cvtpk(acc[dt][r], acc[dt][r + 1]);
    }
}

// ---------------------------------------------------------------------------
// Kernel 3b (fallback path): combine 2 split-K partials -> ao (bf16).
// ---------------------------------------------------------------------------
__global__ __launch_bounds__(256) void combine_splits(
    const unsigned short* __restrict__ opart, const float* __restrict__ lstat,
    unsigned short* __restrict__ ao) {
  const int tid = threadIdx.x;
  const int row = blockIdx.x * 16 + (tid >> 4);
  const int col = (tid & 15) * 8;
  float den = lstat[row] + lstat[32768 + row];
  float inv = 1.f / den;
  float o[8] = {0.f, 0.f, 0.f, 0.f, 0.f, 0.f, 0.f, 0.f};
#pragma unroll
  for (int s = 0; s < 2; ++s) {
    uint4 v = *(const uint4*)(opart + ((size_t)s * 32768 + row) * 128 + col);
    unsigned int uu[4] = {v.x, v.y, v.z, v.w};
#pragma unroll
    for (int j = 0; j < 4; ++j) {
      o[2 * j]     += bf2f((unsigned short)(uu[j] & 0xffff));
      o[2 * j + 1] += bf2f((unsigned short)(uu[j] >> 16));
    }
  }
  uint4 outv;
  outv.x = cvtpk(o[0] * inv, o[1] * inv);
  outv.y = cvtpk(o[2] * inv, o[3] * inv);
  outv.z = cvtpk(o[4] * inv, o[5] * inv);
  outv.w = cvtpk(o[6] * inv, o[7] * inv);
  *(uint4*)(ao + (size_t)row * 128 + col) = outv;
}

// ---------------------------------------------------------------------------
// Kernel 4 (fallback path): output projection + bias + residual.
// ---------------------------------------------------------------------------
__global__ __launch_bounds__(256) void out_proj(
    const unsigned short* __restrict__ ao, const unsigned short* __restrict__ WoT,
    const float* __restrict__ bo, const float* __restrict__ x, float* __restrict__ out) {
  const int pix0 = blockIdx.x * 64;
  const int wave = threadIdx.x >> 6, lane = threadIdx.x & 63, l = lane & 15, qd = lane >> 4;
  const int base = pix0 + wave * 16;
  short8 af[4];
#pragma unroll
  for (int kc = 0; kc < 4; ++kc)
    af[kc] = ld8(ao + (size_t)(base + l) * 128 + kc * 32 + qd * 8);
#pragma unroll
  for (int sub = 0; sub < 16; ++sub) {
    const int c0 = sub * 16 + 4 * qd;
    float4 bb = *(const float4*)(bo + c0);
    f32x4 acc = (f32x4){bb.x, bb.y, bb.z, bb.w};
#pragma unroll
    for (int kc = 0; kc < 4; ++kc) {
      short8 wf = ld8(WoT + (size_t)(sub * 16 + l) * 128 + kc * 32 + qd * 8);
      acc = MFMA(wf, af[kc], acc);   // D[c][pixel]
    }
    float4 xv = *(const float4*)(x + (size_t)(base + l) * 256 + c0);
    float4 res;
    res.x = acc[0] + xv.x;
    res.y = acc[1] + xv.y;
    res.z = acc[2] + xv.z;
    res.w = acc[3] + xv.w;
    *(float4*)(out + (size_t)(base + l) * 256 + c0) = res;
  }
}

// ---------------------------------------------------------------------------
// Kernel 4f (fused path): combine(2 splits) + output projection in ONE kernel.
// opart lives in WORKSPACE (no aliasing with the d_out output write).
// ---------------------------------------------------------------------------
__global__ __launch_bounds__(256) void combine_out(
    const unsigned short* __restrict__ opart, const float* __restrict__ lstat,
    const unsigned short* __restrict__ WoT,
    const float* __restrict__ bo, const float* __restrict__ x, float* __restrict__ out) {
  const int pix0 = blockIdx.x * 64;
  const int wave = threadIdx.x >> 6, lane = threadIdx.x & 63, l = lane & 15, qd = lane >> 4;
  const int base = pix0 + wave * 16;
  const int row = base + l;
  const float den = lstat[row] + lstat[32768 + row];
  const float inv = 1.f / den;
  short8 af[4];
#pragma unroll
  for (int kc = 0; kc < 4; ++kc) {
    float o[8] = {0.f, 0.f, 0.f, 0.f, 0.f, 0.f, 0.f, 0.f};
#pragma unroll
    for (int s = 0; s < 2; ++s) {
      uint4 v = *(const uint4*)(opart + ((size_t)s * 32768 + row) * 128 + kc * 32 + qd * 8);
      unsigned int uu[4] = {v.x, v.y, v.z, v.w};
#pragma unroll
      for (int j = 0; j < 4; ++j) {
        o[2 * j]     += bf2f((unsigned short)(uu[j] & 0xffff));
        o[2 * j + 1] += bf2f((unsigned short)(uu[j] >> 16));
      }
    }
    union { unsigned int u[4]; short8 v8; } pk;
#pragma unroll
    for (int j = 0; j < 4; ++j) pk.u[j] = cvtpk(o[2 * j] * inv, o[2 * j + 1] * inv);
    af[kc] = pk.v8;
  }
#pragma unroll
  for (int sub = 0; sub < 16; ++sub) {
    const int c0 = sub * 16 + 4 * qd;
    float4 bb = *(const float4*)(bo + c0);
    f32x4 acc = (f32x4){bb.x, bb.y, bb.z, bb.w};
#pragma unroll
    for (int kc = 0; kc < 4; ++kc) {
      short8 wf = ld8(WoT + (size_t)(sub * 16 + l) * 128 + kc * 32 + qd * 8);
      acc = MFMA(wf, af[kc], acc);   // D[c][pixel]
    }
    float4 xv = *(const float4*)(x + (size_t)row * 256 + c0);
    float4 res;
    res.x = acc[0] + xv.x;
    res.y = acc[1] + xv.y;
    res.z = acc[2] + xv.z;
    res.w = acc[3] + xv.w;
    *(float4*)(out + (size_t)row * 256 + c0) = res;
  }
}

// ---------------------------------------------------------------------------
extern "C" void kernel_launch(void* const* d_in, const int* in_sizes, int n_in,
                              void* d_out, int out_size, void* d_ws, size_t ws_size,
                              hipStream_t stream) {
  const float* x  = (const float*)d_in[0];
  const float* Wq = (const float*)d_in[1];
  const float* bq = (const float*)d_in[2];
  const float* Wk = (const float*)d_in[3];
  const float* bk = (const float*)d_in[4];
  const float* Wv = (const float*)d_in[5];
  const float* bv = (const float*)d_in[6];
  const float* Wo = (const float*)d_in[7];
  const float* bo = (const float*)d_in[8];

  char* ws = (char*)d_ws;
  // Workspace map (bytes):
  //   qh    @ 0          2 MB   fp16 [32768][32]
  //   KVF   @ 2 MB       10 MB  fused kh(fp16)|V(bf16) frags
  //   Wth   @ 12 MB      96 KB
  //   Wtl   @ +96 KB     96 KB
  //   WoT   @ +192 KB    64 KB
  //   lst   @ +256 KB    256 KB [2][32768]
  //   ao    @ 13,369,344 8 MB   (fallback path only)
  //   opart @ 16 MB      16 MB  (fused path only; needs ws >= 32 MB, gate 48)
  unsigned short* qh  = (unsigned short*)(ws + 0);
  unsigned short* KVF = (unsigned short*)(ws + 2097152);
  unsigned short* Wth = (unsigned short*)(ws + 12582912);
  unsigned short* Wtl = (unsigned short*)(ws + 12681216);
  unsigned short* WoT = (unsigned short*)(ws + 12779520);
  float*          lst = (float*)(ws + 12845056);
  unsigned short* ao  = (unsigned short*)(ws + 13369344);

  const bool fused = (ws_size >= 50331648ull);  // 48 MB gate (proven active)
  unsigned short* opart = fused ? (unsigned short*)(ws + 16777216)
                                : (unsigned short*)d_out;

  prep_weights<<<320, 256, 0, stream>>>(Wq, Wk, Wv, Wo, Wth, Wtl, WoT);
  proj_qkv<<<1024, 256, 0, stream>>>(x, Wth, Wtl, bq, bk, bv, qh, KVF);
  flash_attn<<<512, 256, 0, stream>>>(qh, KVF, opart, lst);
  if (fused) {
    combine_out<<<512, 256, 0, stream>>>(opart, lst, WoT, bo, x, (float*)d_out);
  } else {
    combine_splits<<<2048, 256, 0, stream>>>(opart, lst, ao);
    out_proj<<<512, 256, 0, stream>>>(ao, WoT, bo, x, (float*)d_out);
  }
}